// Round 20
// baseline (105.448 us; speedup 1.0000x reference)
//
#include <hip/hip_runtime.h>
#include <hip/hip_bf16.h>
#include <stdint.h>

typedef unsigned short u16;
typedef __bf16 bf16_t;
typedef bf16_t bf16x8 __attribute__((ext_vector_type(8)));
typedef float f32x4 __attribute__((ext_vector_type(4)));

#define NTOK 32768
#define CEMB 256
#define NHEAD 8
#define HD 32
#define BSEG 128
#define TSEG 256

// 1/sqrt(32) * log2(e): folded into Q at projection time.
#define SCQ (0.17677669529663687f * 1.4426950408889634f)

static __device__ __forceinline__ bf16x8 ld16(const u16* p) {
  uint4 v = *reinterpret_cast<const uint4*>(p);
  return __builtin_bit_cast(bf16x8, v);
}
static __device__ __forceinline__ u16 f2b(float f) {
  return __builtin_bit_cast(u16, (bf16_t)f);
}
static __device__ __forceinline__ float b2f(u16 v) {
  uint32_t u = ((uint32_t)v) << 16;
  return __builtin_bit_cast(float, u);
}
static __device__ __forceinline__ uint4 cvt8(float4 a, float4 b) {
  u16 o[8] = {f2b(a.x), f2b(a.y), f2b(a.z), f2b(a.w),
              f2b(b.x), f2b(b.y), f2b(b.z), f2b(b.w)};
  return *reinterpret_cast<const uint4*>(o);
}

typedef __attribute__((address_space(1))) const void GASV;
typedef __attribute__((address_space(3))) void LASV;
static __device__ __forceinline__ void stage16(const u16* g, u16* l) {
  __builtin_amdgcn_global_load_lds((GASV*)g, (LASV*)l, 16, 0, 0);
}

// ---------------- K1: fused convert + QKV projection ----------------------
// One block per m-tile (grid 256, 1 blk/CU). 1024 threads = 16 waves
// (4m x 4n; wave tile 32x64). LDS (160 KB exactly):
// [0,64K) A bf16 [128][512B] XOR-swizzled, staged once from f32 x;
// [64K,128K) B bf16 DBUF [2][256][128B] swizzled, reg-staged from f32 W;
// [128K,160K) bounce. ONE barrier per phase: compute(par) -> BWRITE(bi+1 ->
// par^1) -> BLOAD(bi+2) -> sync. ds_reads issue before ds_writes; the
// write's vmcnt dependency (BLOAD issued >=1 phase earlier) has landed.
__global__ __launch_bounds__(1024, 1)
void k_qkv(const float* __restrict__ x,
           const float* __restrict__ Wq, const float* __restrict__ Wk,
           const float* __restrict__ Wv,
           const float* __restrict__ bq, const float* __restrict__ bk,
           const float* __restrict__ bv,
           u16* __restrict__ q_ws, u16* __restrict__ k_ws, u16* __restrict__ v_ws) {
  const int d = blockIdx.x;
  const int m_idx = (d & 7) * 32 + (d >> 3);
  const int m0 = m_idx * 128;
  const int tid = threadIdx.x;
  const int w = tid >> 6, l = tid & 63;
  const int lr = l & 15, lg = l >> 4;
  const int wrP = w >> 2, wcP = w & 3;

  extern __shared__ char lds[];
  char* bounce = lds + 131072;

  // ---- B reg-stage helpers (row = tid>>2 in 0..255, two 16B chunks) ----
  const int brow = tid >> 2;
  const int bcb = (tid & 3) * 2;
  float4 breg[2][4];
  auto BLOAD = [&](int bi, float4* r4) {
    const float* Wsel = (bi >> 2) == 0 ? Wq : ((bi >> 2) == 1 ? Wk : Wv);
    const float* s = Wsel + (size_t)brow * CEMB + (bi & 3) * 64 + bcb * 8;
    r4[0] = reinterpret_cast<const float4*>(s)[0];
    r4[1] = reinterpret_cast<const float4*>(s)[1];
    r4[2] = reinterpret_cast<const float4*>(s)[2];
    r4[3] = reinterpret_cast<const float4*>(s)[3];
  };
  auto BWRITE = [&](const float4* r4, int par) {
    char* Bs = lds + 65536 + par * 32768;
#pragma unroll
    for (int jj = 0; jj < 2; ++jj) {
      int byte = brow * 128 + (((bcb + jj) * 16) ^ ((brow & 7) << 4));
      *reinterpret_cast<uint4*>(Bs + byte) = cvt8(r4[jj * 2], r4[jj * 2 + 1]);
    }
  };

  // ---- prologue ----
  BLOAD(0, breg[0]);
  {
    int row = tid >> 3, seg = tid & 7;
    const float* src = x + (size_t)(m0 + row) * CEMB + seg * 32;
#pragma unroll
    for (int j = 0; j < 4; ++j) {
      float4 a = reinterpret_cast<const float4*>(src)[2 * j];
      float4 b = reinterpret_cast<const float4*>(src)[2 * j + 1];
      int byte = row * 512 + ((seg * 64 + j * 16) ^ ((row & 7) << 4));
      *reinterpret_cast<uint4*>(lds + byte) = cvt8(a, b);
    }
  }
  BWRITE(breg[0], 0);
  BLOAD(1, breg[1]);
  __syncthreads();  // A + B(0) ready

#pragma unroll
  for (int mode = 0; mode < 3; ++mode) {
    f32x4 acc[2][4];
#pragma unroll
    for (int mf = 0; mf < 2; ++mf)
#pragma unroll
      for (int nf = 0; nf < 4; ++nf) {
        f32x4 z = {0.f, 0.f, 0.f, 0.f};
        acc[mf][nf] = z;
      }

#pragma unroll
    for (int kt = 0; kt < 4; ++kt) {
      const int bi = mode * 4 + kt;
      const int par = bi & 1;
      const char* Bs = lds + 65536 + par * 32768;
      bf16x8 av[2][2], bw[4][2];
#pragma unroll
      for (int mf = 0; mf < 2; ++mf)
#pragma unroll
        for (int kk = 0; kk < 2; ++kk) {
          int row = wrP * 32 + mf * 16 + lr;
          int byte = row * 512 + ((kt * 128 + kk * 64 + lg * 16) ^ ((row & 7) << 4));
          av[mf][kk] = *reinterpret_cast<const bf16x8*>(lds + byte);
        }
#pragma unroll
      for (int nf = 0; nf < 4; ++nf)
#pragma unroll
        for (int kk = 0; kk < 2; ++kk) {
          int row = wcP * 64 + nf * 16 + lr;
          int byte = row * 128 + ((kk * 64 + lg * 16) ^ ((row & 7) << 4));
          bw[nf][kk] = *reinterpret_cast<const bf16x8*>(Bs + byte);
        }
#pragma unroll
      for (int kk = 0; kk < 2; ++kk)
#pragma unroll
        for (int nf = 0; nf < 4; ++nf)
#pragma unroll
          for (int mf = 0; mf < 2; ++mf)
            acc[mf][nf] = __builtin_amdgcn_mfma_f32_16x16x32_bf16(
                av[mf][kk], bw[nf][kk], acc[mf][nf], 0, 0, 0);
      if (bi < 11) BWRITE(breg[(bi + 1) & 1], par ^ 1);
      if (bi < 10) BLOAD(bi + 2, breg[bi & 1]);
      __syncthreads();  // par reads done + par^1 writes visible
    }

    // ---- epilogue for this mode ----
    const float* bias = (mode == 0) ? bq : ((mode == 1) ? bk : bv);
    float bb[4];
#pragma unroll
    for (int nf = 0; nf < 4; ++nf) bb[nf] = bias[wcP * 64 + nf * 16 + lr];

    if (mode < 2) {
      const float osc = (mode == 0) ? SCQ : 1.0f;
      u16* outp = (mode == 0) ? q_ws : k_ws;
#pragma unroll
      for (int g = 0; g < 2; ++g) {
        if ((wrP >> 1) == g) {
#pragma unroll
          for (int mf = 0; mf < 2; ++mf)
#pragma unroll
            for (int nf = 0; nf < 4; ++nf)
#pragma unroll
              for (int r = 0; r < 4; ++r) {
                int lrow = (wrP & 1) * 32 + mf * 16 + lg * 4 + r;
                int col = wcP * 64 + nf * 16 + lr;
                int byte = lrow * 512 + ((col * 2) ^ ((lrow & 7) << 4));
                *(u16*)(bounce + byte) = f2b((acc[mf][nf][r] + bb[nf]) * osc);
              }
        }
        __syncthreads();
#pragma unroll
        for (int jj = 0; jj < 2; ++jj) {
          int ch = tid * 2 + jj;
          int crow = ch >> 5, cc = ch & 31;
          int byte = crow * 512 + ((cc * 16) ^ ((crow & 7) << 4));
          *reinterpret_cast<uint4*>(outp + (size_t)(m0 + g * 64 + crow) * CEMB + cc * 8) =
              *reinterpret_cast<const uint4*>(bounce + byte);
        }
        __syncthreads();
      }
    } else {
      const int bs = m0 >> 8, t0 = m0 & 255;
#pragma unroll
      for (int g = 0; g < 2; ++g) {
        if ((wcP >> 1) == g) {
#pragma unroll
          for (int mf = 0; mf < 2; ++mf)
#pragma unroll
            for (int nf = 0; nf < 4; ++nf)
#pragma unroll
              for (int r = 0; r < 4; ++r) {
                int row = wrP * 32 + mf * 16 + lg * 4 + r;
                int ccol = (wcP & 1) * 64 + nf * 16 + lr;
                int byte = ccol * 256 + ((row * 2) ^ ((ccol & 7) << 4));
                *(u16*)(bounce + byte) = f2b(acc[mf][nf][r] + bb[nf]);
              }
        }
        __syncthreads();
#pragma unroll
        for (int jj = 0; jj < 2; ++jj) {
          int ch = tid * 2 + jj;
          int ccl = ch >> 4, cc = ch & 15;
          int byte = ccl * 256 + ((cc * 16) ^ ((ccl & 7) << 4));
          int c = g * 128 + ccl, hh = c >> 5, dd = c & 31;
          *reinterpret_cast<uint4*>(
              v_ws + ((size_t)(bs * NHEAD + hh) * HD + dd) * TSEG + t0 + cc * 8) =
              *reinterpret_cast<const uint4*>(bounce + byte);
        }
        __syncthreads();
      }
    }
  }
}

// ---------------- K2: attention + fused output projection ----------------
// s-split + LDS-staged KV dbuf + T5 setprio + fused proj; B2 DELETED:
// publishes (sm -> dbuf'd smb, partner y-half raw bf16 -> final yTile slot)
// are fenced by the NEXT head's B1; each wave finishes head h-1 (inv, macc,
// yTile RMW) after B1 of head h. Tail finishes head 7.
__global__ __launch_bounds__(1024, 1)
void k_attn(const u16* __restrict__ q_ws, const u16* __restrict__ k_ws,
            const u16* __restrict__ v_ws, const float* __restrict__ Wp,
            const float* __restrict__ bp,
            float* __restrict__ out, float* __restrict__ mean_out) {
  const int dblk = blockIdx.x;
  const int xcd = dblk & 7, ii = dblk >> 3;  // ii in 0..31
  const int b = xcd * 16 + (ii >> 1);
  const int th = ii & 1;
  const int tid = threadIdx.x;
  const int w = tid >> 6, l = tid & 63;
  const int lr = l & 15, lg = l >> 4;
  const int wt = w & 7, sh = w >> 3;
  const int tbase = th * 128 + wt * 16;

  extern __shared__ u16 ldsKV[];
  float* smb = reinterpret_cast<float*>(ldsKV + 32768);   // [2][16 slots][16]
  char* yTile = reinterpret_cast<char*>(ldsKV) + 83968;

  float macc[8][4];
#pragma unroll
  for (int st = 0; st < 8; ++st)
#pragma unroll
    for (int r = 0; r < 4; ++r) macc[st][r] = 0.f;

  const u16* qseg = q_ws + (size_t)b * TSEG * CEMB;
  const u16* kseg = k_ws + (size_t)b * TSEG * CEMB;
  const u16* vseg = v_ws + (size_t)(b * NHEAD) * HD * TSEG;

  auto STAGE_KV = [&](int hn, int bn) {
    int idx = tid;                       // 0..1023 chunk id
    int c = idx >> 6, l2 = idx & 63;     // frag, lane
    int lr2 = l2 & 15, lg2 = l2 >> 4;
    int srow = 32 * (c >> 1) + 4 * (c & 1) + 8 * (lr2 >> 2) + (lr2 & 3);
    stage16(kseg + srow * CEMB + hn * HD + lg2 * 8, ldsKV + (bn * 1024 + idx) * 8);
    int vrow = (c >> 3) * 16 + lr2;
    int vcol = (c & 7) * 32 + lg2 * 8;
    stage16(vseg + (size_t)(hn * HD + vrow) * TSEG + vcol,
            ldsKV + 16384 + (bn * 1024 + idx) * 8);
  };

  STAGE_KV(0, 0);
  bf16x8 qf = ld16(qseg + (tbase + lr) * CEMB + lg * 8);

  const int own_slot = wt * 2 + sh;
  const int par_slot = wt * 2 + (1 - sh);
  const int yrow = wt * 16 + lr;

  float s[8][4];
  float sm = 0.f;
  f32x4 ymine = {0.f, 0.f, 0.f, 0.f};

  for (int h = 0; h < NHEAD; ++h) {
    const int bn = h & 1;
    __syncthreads();  // B1: drains stage(h) + qf + head h-1 publishes
    if (h < 7) STAGE_KV(h + 1, bn ^ 1);

    // ---- finish head h-1 (partner publishes now visible) ----
    if (h > 0) {
      const int hp = h - 1;
      float smT = sm + smb[(hp & 1) * 256 + par_slot * 16 + lr];
      float inv = __builtin_amdgcn_rcpf(smT);
#pragma unroll
      for (int st = 0; st < 8; ++st)
#pragma unroll
        for (int r = 0; r < 4; ++r)
          macc[st][r] = fmaf(s[st][r], inv, macc[st][r]);
      int colb = hp * 64 + sh * 32 + lg * 8;
      char* yp = yTile + yrow * 512 + (colb ^ ((yrow & 7) << 4));
      uint2 part = *reinterpret_cast<const uint2*>(yp);
      const u16* pw = reinterpret_cast<const u16*>(&part);
      u16 o[4];
#pragma unroll
      for (int r = 0; r < 4; ++r)
        o[r] = f2b((ymine[r] + b2f(pw[r])) * inv);
      *reinterpret_cast<uint2*>(yp) = *reinterpret_cast<const uint2*>(o);
    }

    const u16* Kb = ldsKV + bn * 8192;
    const u16* Vb = ldsKV + 16384 + bn * 8192;

    __builtin_amdgcn_s_setprio(1);
#pragma unroll
    for (int st = 0; st < 8; ++st) {
      bf16x8 kf = *reinterpret_cast<const bf16x8*>(Kb + ((sh * 8 + st) * 64 + l) * 8);
      f32x4 z = {0.f, 0.f, 0.f, 0.f};
      f32x4 dd = __builtin_amdgcn_mfma_f32_16x16x32_bf16(kf, qf, z, 0, 0, 0);
#pragma unroll
      for (int r = 0; r < 4; ++r) s[st][r] = dd[r];
    }
    __builtin_amdgcn_s_setprio(0);

    qf = ld16(qseg + (tbase + lr) * CEMB + ((h + 1) & 7) * HD + lg * 8);

    float s0 = 0.f, s1 = 0.f, s2 = 0.f, s3 = 0.f;
#pragma unroll
    for (int st = 0; st < 8; ++st) {
      float p0 = exp2f(s[st][0]);
      float p1 = exp2f(s[st][1]);
      float p2 = exp2f(s[st][2]);
      float p3 = exp2f(s[st][3]);
      s[st][0] = p0; s[st][1] = p1; s[st][2] = p2; s[st][3] = p3;
      s0 += p0; s1 += p1; s2 += p2; s3 += p3;
    }
    sm = (s0 + s1) + (s2 + s3);
    sm += __shfl_xor(sm, 16, 64);
    sm += __shfl_xor(sm, 32, 64);

    bf16x8 pb[4];
#pragma unroll
    for (int kk = 0; kk < 4; ++kk)
#pragma unroll
      for (int e = 0; e < 4; ++e) {
        pb[kk][e] = (bf16_t)s[2 * kk][e];
        pb[kk][4 + e] = (bf16_t)s[2 * kk + 1][e];
      }

    f32x4 y0 = {0.f, 0.f, 0.f, 0.f}, y1 = {0.f, 0.f, 0.f, 0.f};
    __builtin_amdgcn_s_setprio(1);
#pragma unroll
    for (int kk = 0; kk < 4; ++kk) {
      bf16x8 vf0 = *reinterpret_cast<const bf16x8*>(Vb + ((0 * 8 + sh * 4 + kk) * 64 + l) * 8);
      bf16x8 vf1 = *reinterpret_cast<const bf16x8*>(Vb + ((1 * 8 + sh * 4 + kk) * 64 + l) * 8);
      y0 = __builtin_amdgcn_mfma_f32_16x16x32_bf16(vf0, pb[kk], y0, 0, 0, 0);
      y1 = __builtin_amdgcn_mfma_f32_16x16x32_bf16(vf1, pb[kk], y1, 0, 0, 0);
    }
    __builtin_amdgcn_s_setprio(0);

    // ---- publish (no barrier; next B1 fences) ----
    if (l < 16) smb[(h & 1) * 256 + own_slot * 16 + l] = sm;
    {
      f32x4 yo = (sh == 0) ? y1 : y0;   // the dt = 1-sh half, raw, bf16
      int colb = h * 64 + (1 - sh) * 32 + lg * 8;
      u16 o[4] = {f2b(yo[0]), f2b(yo[1]), f2b(yo[2]), f2b(yo[3])};
      *reinterpret_cast<uint2*>(yTile + yrow * 512 + (colb ^ ((yrow & 7) << 4))) =
          *reinterpret_cast<const uint2*>(o);
    }
    ymine = (sh == 0) ? y0 : y1;
  }

  __syncthreads();  // head-7 publishes visible

  // ---- finish head 7 ----
  {
    const int hp = 7;
    float smT = sm + smb[(hp & 1) * 256 + par_slot * 16 + lr];
    float inv = __builtin_amdgcn_rcpf(smT);
#pragma unroll
    for (int st = 0; st < 8; ++st)
#pragma unroll
      for (int r = 0; r < 4; ++r)
        macc[st][r] = fmaf(s[st][r], inv, macc[st][r]);
    int colb = hp * 64 + sh * 32 + lg * 8;
    char* yp = yTile + yrow * 512 + (colb ^ ((yrow & 7) << 4));
    uint2 part = *reinterpret_cast<const uint2*>(yp);
    const u16* pw = reinterpret_cast<const u16*>(&part);
    u16 o[4];
#pragma unroll
    for (int r = 0; r < 4; ++r)
      o[r] = f2b((ymine[r] + b2f(pw[r])) * inv);
    *reinterpret_cast<uint2*>(yp) = *reinterpret_cast<const uint2*>(o);
  }

  // W reg-stage helpers (row = tid>>2 in 0..255, two 16B chunks)
  const int wrow = tid >> 2;
  const int wcb = (tid & 3) * 2;
  float4 wreg[2][4];
  auto WLOAD = [&](int kt, float4* r4) {
    const float* s2 = Wp + (size_t)wrow * CEMB + kt * 64 + wcb * 8;
    r4[0] = reinterpret_cast<const float4*>(s2)[0];
    r4[1] = reinterpret_cast<const float4*>(s2)[1];
    r4[2] = reinterpret_cast<const float4*>(s2)[2];
    r4[3] = reinterpret_cast<const float4*>(s2)[3];
  };
  auto WWRITE = [&](const float4* r4, int bn) {
#pragma unroll
    for (int jj = 0; jj < 2; ++jj) {
      int byte = bn * 32768 + wrow * 128 + (((wcb + jj) * 16) ^ ((wrow & 7) << 4));
      *reinterpret_cast<uint4*>(reinterpret_cast<char*>(ldsKV) + byte) =
          cvt8(r4[jj * 2], r4[jj * 2 + 1]);
    }
  };

  WLOAD(0, wreg[0]);  // latency covered by mean epilogue below

  // ---- head-mean epilogue (wave-private staging in KV region) ----
  {
    float* smem = reinterpret_cast<float*>(ldsKV);
    float* smw = smem + w * (16 * 65) + lr * 65;
    const int trow = l >> 2;
    const int cql = (l & 3) * 4;
    const float* srcp = smem + w * (16 * 65) + trow * 65 + cql;
    float* gdst = mean_out + (size_t)(b * TSEG + tbase + trow) * TSEG + sh * 128 + cql;
    for (int c = 0; c < 2; ++c) {
#pragma unroll
      for (int j = 0; j < 4; ++j) {
        int st = 4 * c + j;
        int sl = 32 * ((st >> 1) & 1) + 4 * (st & 1) + 8 * lg;
#pragma unroll
        for (int r = 0; r < 4; ++r) smw[sl + r] = macc[st][r] * 0.125f;
      }
#pragma unroll
      for (int j = 0; j < 4; ++j)
        *reinterpret_cast<f32x4*>(gdst + c * 64 + j * 16) =
            *reinterpret_cast<const f32x4*>(srcp + j * 16);
    }
  }
  __syncthreads();  // mean staging + head-7 yTile RMW done; KV region free

  // ---- fused output projection: out = y * Wp^T + bp ----
  {
    const int wrP = w >> 2, wcP = w & 3;

    WWRITE(wreg[0], 0);
    WLOAD(1, wreg[1]);
    __syncthreads();

    f32x4 acc[2][4];
#pragma unroll
    for (int mf = 0; mf < 2; ++mf)
#pragma unroll
      for (int nf = 0; nf < 4; ++nf) {
        f32x4 z = {0.f, 0.f, 0.f, 0.f};
        acc[mf][nf] = z;
      }

#pragma unroll
    for (int kt = 0; kt < 4; ++kt) {
      int buf = kt & 1;
      if (kt < 3) WWRITE(wreg[(kt + 1) & 1], buf ^ 1);
      if (kt < 2) WLOAD(kt + 2, wreg[kt & 1]);
      const char* Wb = reinterpret_cast<const char*>(ldsKV) + buf * 32768;
      bf16x8 av[2][2], bw[4][2];
#pragma unroll
      for (int mf = 0; mf < 2; ++mf)
#pragma unroll
        for (int kk = 0; kk < 2; ++kk) {
          int row = wrP * 32 + mf * 16 + lr;
          int byte = row * 512 + ((kt * 128 + kk * 64 + lg * 16) ^ ((row & 7) << 4));
          av[mf][kk] = *reinterpret_cast<const bf16x8*>(yTile + byte);
        }
#pragma unroll
      for (int nf = 0; nf < 4; ++nf)
#pragma unroll
        for (int kk = 0; kk < 2; ++kk) {
          int row = wcP * 64 + nf * 16 + lr;
          int byte = row * 128 + ((kk * 64 + lg * 16) ^ ((row & 7) << 4));
          bw[nf][kk] = *reinterpret_cast<const bf16x8*>(Wb + byte);
        }
#pragma unroll
      for (int kk = 0; kk < 2; ++kk)
#pragma unroll
        for (int nf = 0; nf < 4; ++nf)
#pragma unroll
          for (int mf = 0; mf < 2; ++mf)
            acc[mf][nf] = __builtin_amdgcn_mfma_f32_16x16x32_bf16(
                av[mf][kk], bw[nf][kk], acc[mf][nf], 0, 0, 0);
      __syncthreads();
    }

    float bb[4];
#pragma unroll
    for (int nf = 0; nf < 4; ++nf) bb[nf] = bp[wcP * 64 + nf * 16 + lr];
#pragma unroll
    for (int mf = 0; mf < 2; ++mf)
#pragma unroll
      for (int nf = 0; nf < 4; ++nf)
#pragma unroll
        for (int r = 0; r < 4; ++r) {
          int m = b * TSEG + th * 128 + wrP * 32 + mf * 16 + lg * 4 + r;
          int c = wcP * 64 + nf * 16 + lr;
          out[(size_t)m * CEMB + c] = acc[mf][nf][r] + bb[nf];
        }
  }
}

extern "C" void kernel_launch(void* const* d_in, const int* in_sizes, int n_in,
                              void* d_out, int out_size, void* d_ws, size_t ws_size,
                              hipStream_t stream) {
  (void)in_sizes; (void)n_in; (void)out_size; (void)ws_size;
  const float* x  = (const float*)d_in[0];
  // d_in[1] = batch indices (unused: equal-length segments, B=128, T=256)
  const float* Wq = (const float*)d_in[2];
  const float* bq = (const float*)d_in[3];
  const float* Wk = (const float*)d_in[4];
  const float* bk = (const float*)d_in[5];
  const float* Wv = (const float*)d_in[6];
  const float* bv = (const float*)d_in[7];
  const float* Wp = (const float*)d_in[8];
  const float* bp = (const float*)d_in[9];
  float* out = (float*)d_out;

  char* ws = (char*)d_ws;
  u16* q_ws = (u16*)(ws);                    // 16 MiB, plain [m][256], pre-scaled
  u16* k_ws = (u16*)(ws + 16777216);         // 16 MiB, plain [m][256]
  u16* v_ws = (u16*)(ws + 33554432);         // 16 MiB, transposed [b,h,d,t]
  float* mean_out = out + (size_t)NTOK * CEMB;

  k_qkv<<<256, 1024, 163840, stream>>>(x, Wq, Wk, Wv, bq, bk, bv, q_ws, k_ws, v_ws);
  k_attn<<<256, 1024, 149504, stream>>>(q_ws, k_ws, v_ws, Wp, bp, out, mean_out);
}

// Round 21
// 83.017 us; speedup vs baseline: 1.2702x; 1.2702x over previous
//
#include <hip/hip_runtime.h>
#include <hip/hip_bf16.h>
#include <stdint.h>

typedef unsigned short u16;
typedef __bf16 bf16_t;
typedef bf16_t bf16x8 __attribute__((ext_vector_type(8)));
typedef float f32x4 __attribute__((ext_vector_type(4)));

#define NTOK 32768
#define CEMB 256
#define NHEAD 8
#define HD 32
#define BSEG 128
#define TSEG 256

// 1/sqrt(32) * log2(e): folded into Q at projection time.
#define SCQ (0.17677669529663687f * 1.4426950408889634f)

static __device__ __forceinline__ bf16x8 ld16(const u16* p) {
  uint4 v = *reinterpret_cast<const uint4*>(p);
  return __builtin_bit_cast(bf16x8, v);
}
static __device__ __forceinline__ u16 f2b(float f) {
  return __builtin_bit_cast(u16, (bf16_t)f);
}
static __device__ __forceinline__ uint4 cvt8(float4 a, float4 b) {
  u16 o[8] = {f2b(a.x), f2b(a.y), f2b(a.z), f2b(a.w),
              f2b(b.x), f2b(b.y), f2b(b.z), f2b(b.w)};
  return *reinterpret_cast<const uint4*>(o);
}

typedef __attribute__((address_space(1))) const void GASV;
typedef __attribute__((address_space(3))) void LASV;
static __device__ __forceinline__ void stage16(const u16* g, u16* l) {
  __builtin_amdgcn_global_load_lds((GASV*)g, (LASV*)l, 16, 0, 0);
}

// ---------------- K1: fused convert + QKV projection (R14 schedule) -------
// One block per m-tile (grid 256, 1 blk/CU, LDS-capped). 1024 threads = 16
// waves (4m x 4n over the 128x256 tile; wave tile 32x64).
// LDS (128 KB): [0,64K) A bf16 [128 rows][512B] XOR-swizzled, staged ONCE
// from f32 x (reg-staged cvt); [64K,96K) B bf16 [256 n][128B] swizzled,
// single-buffered, reg-staged from f32 W (compute -> barrier -> write ->
// load -> barrier); [96K,128K) bounce for coalesced epilogues.
__global__ __launch_bounds__(1024, 1)
void k_qkv(const float* __restrict__ x,
           const float* __restrict__ Wq, const float* __restrict__ Wk,
           const float* __restrict__ Wv,
           const float* __restrict__ bq, const float* __restrict__ bk,
           const float* __restrict__ bv,
           u16* __restrict__ q_ws, u16* __restrict__ k_ws, u16* __restrict__ v_ws) {
  const int d = blockIdx.x;
  const int m_idx = (d & 7) * 32 + (d >> 3);
  const int m0 = m_idx * 128;
  const int tid = threadIdx.x;
  const int w = tid >> 6, l = tid & 63;
  const int lr = l & 15, lg = l >> 4;
  const int wrP = w >> 2, wcP = w & 3;

  extern __shared__ char lds[];
  char* Bs = lds + 65536;
  char* bounce = lds + 98304;

  // ---- B reg-stage helpers (row = tid>>2 in 0..255, two 16B chunks) ----
  const int brow = tid >> 2;
  const int bcb = (tid & 3) * 2;
  float4 breg[2][4];
  auto BLOAD = [&](int bi, float4* r4) {
    const float* Wsel = (bi >> 2) == 0 ? Wq : ((bi >> 2) == 1 ? Wk : Wv);
    const float* s = Wsel + (size_t)brow * CEMB + (bi & 3) * 64 + bcb * 8;
    r4[0] = reinterpret_cast<const float4*>(s)[0];
    r4[1] = reinterpret_cast<const float4*>(s)[1];
    r4[2] = reinterpret_cast<const float4*>(s)[2];
    r4[3] = reinterpret_cast<const float4*>(s)[3];
  };
  auto BWRITE = [&](const float4* r4) {
#pragma unroll
    for (int jj = 0; jj < 2; ++jj) {
      int byte = brow * 128 + (((bcb + jj) * 16) ^ ((brow & 7) << 4));
      *reinterpret_cast<uint4*>(Bs + byte) = cvt8(r4[jj * 2], r4[jj * 2 + 1]);
    }
  };

  // ---- prologue: issue B(0) loads, stage A (f32 -> bf16, swizzled) ----
  BLOAD(0, breg[0]);
  {
    int row = tid >> 3, seg = tid & 7;
    const float* src = x + (size_t)(m0 + row) * CEMB + seg * 32;
#pragma unroll
    for (int j = 0; j < 4; ++j) {
      float4 a = reinterpret_cast<const float4*>(src)[2 * j];
      float4 b = reinterpret_cast<const float4*>(src)[2 * j + 1];
      int byte = row * 512 + ((seg * 64 + j * 16) ^ ((row & 7) << 4));
      *reinterpret_cast<uint4*>(lds + byte) = cvt8(a, b);
    }
  }
  BWRITE(breg[0]);
  BLOAD(1, breg[1]);
  __syncthreads();

#pragma unroll
  for (int mode = 0; mode < 3; ++mode) {
    f32x4 acc[2][4];
#pragma unroll
    for (int mf = 0; mf < 2; ++mf)
#pragma unroll
      for (int nf = 0; nf < 4; ++nf) {
        f32x4 z = {0.f, 0.f, 0.f, 0.f};
        acc[mf][nf] = z;
      }

#pragma unroll
    for (int kt = 0; kt < 4; ++kt) {
      const int bi = mode * 4 + kt;
      // compute (A persistent, B in Bs)
      bf16x8 av[2][2], bw[4][2];
#pragma unroll
      for (int mf = 0; mf < 2; ++mf)
#pragma unroll
        for (int kk = 0; kk < 2; ++kk) {
          int row = wrP * 32 + mf * 16 + lr;
          int byte = row * 512 + ((kt * 128 + kk * 64 + lg * 16) ^ ((row & 7) << 4));
          av[mf][kk] = *reinterpret_cast<const bf16x8*>(lds + byte);
        }
#pragma unroll
      for (int nf = 0; nf < 4; ++nf)
#pragma unroll
        for (int kk = 0; kk < 2; ++kk) {
          int row = wcP * 64 + nf * 16 + lr;
          int byte = row * 128 + ((kk * 64 + lg * 16) ^ ((row & 7) << 4));
          bw[nf][kk] = *reinterpret_cast<const bf16x8*>(Bs + byte);
        }
#pragma unroll
      for (int kk = 0; kk < 2; ++kk)
#pragma unroll
        for (int nf = 0; nf < 4; ++nf)
#pragma unroll
          for (int mf = 0; mf < 2; ++mf)
            acc[mf][nf] = __builtin_amdgcn_mfma_f32_16x16x32_bf16(
                av[mf][kk], bw[nf][kk], acc[mf][nf], 0, 0, 0);
      if (bi < 11) {
        __syncthreads();  // B(bi) consumed by all waves
        BWRITE(breg[(bi + 1) & 1]);
        if (bi < 10) BLOAD(bi + 2, breg[bi & 1]);
        __syncthreads();  // B(bi+1) visible
      }
    }

    // ---- epilogue for this mode ----
    const float* bias = (mode == 0) ? bq : ((mode == 1) ? bk : bv);
    float bb[4];
#pragma unroll
    for (int nf = 0; nf < 4; ++nf) bb[nf] = bias[wcP * 64 + nf * 16 + lr];

    if (mode < 2) {
      const float osc = (mode == 0) ? SCQ : 1.0f;
      u16* outp = (mode == 0) ? q_ws : k_ws;
#pragma unroll
      for (int g = 0; g < 2; ++g) {
        if ((wrP >> 1) == g) {
#pragma unroll
          for (int mf = 0; mf < 2; ++mf)
#pragma unroll
            for (int nf = 0; nf < 4; ++nf)
#pragma unroll
              for (int r = 0; r < 4; ++r) {
                int lrow = (wrP & 1) * 32 + mf * 16 + lg * 4 + r;
                int col = wcP * 64 + nf * 16 + lr;
                int byte = lrow * 512 + ((col * 2) ^ ((lrow & 7) << 4));
                *(u16*)(bounce + byte) = f2b((acc[mf][nf][r] + bb[nf]) * osc);
              }
        }
        __syncthreads();
#pragma unroll
        for (int jj = 0; jj < 2; ++jj) {
          int ch = tid * 2 + jj;
          int crow = ch >> 5, cc = ch & 31;
          int byte = crow * 512 + ((cc * 16) ^ ((crow & 7) << 4));
          *reinterpret_cast<uint4*>(outp + (size_t)(m0 + g * 64 + crow) * CEMB + cc * 8) =
              *reinterpret_cast<const uint4*>(bounce + byte);
        }
        __syncthreads();
      }
    } else {
      const int bs = m0 >> 8, t0 = m0 & 255;
#pragma unroll
      for (int g = 0; g < 2; ++g) {
        if ((wcP >> 1) == g) {
#pragma unroll
          for (int mf = 0; mf < 2; ++mf)
#pragma unroll
            for (int nf = 0; nf < 4; ++nf)
#pragma unroll
              for (int r = 0; r < 4; ++r) {
                int row = wrP * 32 + mf * 16 + lg * 4 + r;
                int ccol = (wcP & 1) * 64 + nf * 16 + lr;
                int byte = ccol * 256 + ((row * 2) ^ ((ccol & 7) << 4));
                *(u16*)(bounce + byte) = f2b(acc[mf][nf][r] + bb[nf]);
              }
        }
        __syncthreads();
#pragma unroll
        for (int jj = 0; jj < 2; ++jj) {
          int ch = tid * 2 + jj;
          int ccl = ch >> 4, cc = ch & 15;
          int byte = ccl * 256 + ((cc * 16) ^ ((ccl & 7) << 4));
          int c = g * 128 + ccl, hh = c >> 5, dd = c & 31;
          *reinterpret_cast<uint4*>(
              v_ws + ((size_t)(bs * NHEAD + hh) * HD + dd) * TSEG + t0 + cc * 8) =
              *reinterpret_cast<const uint4*>(bounce + byte);
        }
        __syncthreads();
      }
    }
  }
}

// ---------------- K2: attention + fused output projection ----------------
// R16/R19 structure: s-split + LDS-staged KV dbuf + lgkm-only mid barrier +
// T5 s_setprio + fused proj (f32 Wp reg-staged).
__global__ __launch_bounds__(1024, 1)
void k_attn(const u16* __restrict__ q_ws, const u16* __restrict__ k_ws,
            const u16* __restrict__ v_ws, const float* __restrict__ Wp,
            const float* __restrict__ bp,
            float* __restrict__ out, float* __restrict__ mean_out) {
  const int dblk = blockIdx.x;
  const int xcd = dblk & 7, ii = dblk >> 3;  // ii in 0..31
  const int b = xcd * 16 + (ii >> 1);
  const int th = ii & 1;
  const int tid = threadIdx.x;
  const int w = tid >> 6, l = tid & 63;
  const int lr = l & 15, lg = l >> 4;
  const int wt = w & 7, sh = w >> 3;
  const int tbase = th * 128 + wt * 16;

  extern __shared__ u16 ldsKV[];
  float* smb = reinterpret_cast<float*>(ldsKV + 32768);
  float* ylds = reinterpret_cast<float*>(ldsKV + 33280);
  char* yTile = reinterpret_cast<char*>(ldsKV) + 83968;

  float macc[8][4];
#pragma unroll
  for (int st = 0; st < 8; ++st)
#pragma unroll
    for (int r = 0; r < 4; ++r) macc[st][r] = 0.f;

  const u16* qseg = q_ws + (size_t)b * TSEG * CEMB;
  const u16* kseg = k_ws + (size_t)b * TSEG * CEMB;
  const u16* vseg = v_ws + (size_t)(b * NHEAD) * HD * TSEG;

  auto STAGE_KV = [&](int hn, int bn) {
    int idx = tid;                       // 0..1023 chunk id
    int c = idx >> 6, l2 = idx & 63;     // frag, lane
    int lr2 = l2 & 15, lg2 = l2 >> 4;
    int srow = 32 * (c >> 1) + 4 * (c & 1) + 8 * (lr2 >> 2) + (lr2 & 3);
    stage16(kseg + srow * CEMB + hn * HD + lg2 * 8, ldsKV + (bn * 1024 + idx) * 8);
    int vrow = (c >> 3) * 16 + lr2;
    int vcol = (c & 7) * 32 + lg2 * 8;
    stage16(vseg + (size_t)(hn * HD + vrow) * TSEG + vcol,
            ldsKV + 16384 + (bn * 1024 + idx) * 8);
  };

  STAGE_KV(0, 0);
  bf16x8 qf = ld16(qseg + (tbase + lr) * CEMB + lg * 8);

  const int own_slot = wt * 2 + sh;
  const int par_slot = wt * 2 + (1 - sh);

  for (int h = 0; h < NHEAD; ++h) {
    const int bn = h & 1;
    __syncthreads();  // B1: vmcnt drain (stage h + qf) + barrier
    if (h < 7) STAGE_KV(h + 1, bn ^ 1);
    const u16* Kb = ldsKV + bn * 8192;
    const u16* Vb = ldsKV + 16384 + bn * 8192;

    float s[8][4];
    __builtin_amdgcn_s_setprio(1);
#pragma unroll
    for (int st = 0; st < 8; ++st) {
      bf16x8 kf = *reinterpret_cast<const bf16x8*>(Kb + ((sh * 8 + st) * 64 + l) * 8);
      f32x4 z = {0.f, 0.f, 0.f, 0.f};
      f32x4 dd = __builtin_amdgcn_mfma_f32_16x16x32_bf16(kf, qf, z, 0, 0, 0);
#pragma unroll
      for (int r = 0; r < 4; ++r) s[st][r] = dd[r];
    }
    __builtin_amdgcn_s_setprio(0);

    qf = ld16(qseg + (tbase + lr) * CEMB + ((h + 1) & 7) * HD + lg * 8);

    float s0 = 0.f, s1 = 0.f, s2 = 0.f, s3 = 0.f;
#pragma unroll
    for (int st = 0; st < 8; ++st) {
      float p0 = exp2f(s[st][0]);
      float p1 = exp2f(s[st][1]);
      float p2 = exp2f(s[st][2]);
      float p3 = exp2f(s[st][3]);
      s[st][0] = p0; s[st][1] = p1; s[st][2] = p2; s[st][3] = p3;
      s0 += p0; s1 += p1; s2 += p2; s3 += p3;
    }
    float sm = (s0 + s1) + (s2 + s3);
    sm += __shfl_xor(sm, 16, 64);
    sm += __shfl_xor(sm, 32, 64);

    bf16x8 pb[4];
#pragma unroll
    for (int kk = 0; kk < 4; ++kk)
#pragma unroll
      for (int e = 0; e < 4; ++e) {
        pb[kk][e] = (bf16_t)s[2 * kk][e];
        pb[kk][4 + e] = (bf16_t)s[2 * kk + 1][e];
      }

    f32x4 y0 = {0.f, 0.f, 0.f, 0.f}, y1 = {0.f, 0.f, 0.f, 0.f};
    __builtin_amdgcn_s_setprio(1);
#pragma unroll
    for (int kk = 0; kk < 4; ++kk) {
      bf16x8 vf0 = *reinterpret_cast<const bf16x8*>(Vb + ((0 * 8 + sh * 4 + kk) * 64 + l) * 8);
      bf16x8 vf1 = *reinterpret_cast<const bf16x8*>(Vb + ((1 * 8 + sh * 4 + kk) * 64 + l) * 8);
      y0 = __builtin_amdgcn_mfma_f32_16x16x32_bf16(vf0, pb[kk], y0, 0, 0, 0);
      y1 = __builtin_amdgcn_mfma_f32_16x16x32_bf16(vf1, pb[kk], y1, 0, 0, 0);
    }
    __builtin_amdgcn_s_setprio(0);

    if (l < 16) smb[own_slot * 16 + l] = sm;
    {
      f32x4 ywr = (sh == 0) ? y1 : y0;
      *reinterpret_cast<f32x4*>(ylds + own_slot * 272 + lg * 68 + lr * 4) = ywr;
    }

    // B2: lgkm-only barrier — stage(h+1) gloads stay in flight
    __builtin_amdgcn_sched_barrier(0);
    asm volatile("s_waitcnt lgkmcnt(0)" ::: "memory");
    __builtin_amdgcn_s_barrier();
    __builtin_amdgcn_sched_barrier(0);

    float smT = sm + smb[par_slot * 16 + lr];
    float inv = __builtin_amdgcn_rcpf(smT);

#pragma unroll
    for (int st = 0; st < 8; ++st)
#pragma unroll
      for (int r = 0; r < 4; ++r)
        macc[st][r] = fmaf(s[st][r], inv, macc[st][r]);

    {
      f32x4 ymine = (sh == 0) ? y0 : y1;
      f32x4 ypar = *reinterpret_cast<const f32x4*>(ylds + par_slot * 272 + lg * 68 + lr * 4);
      u16 o[4];
#pragma unroll
      for (int r = 0; r < 4; ++r) o[r] = f2b((ymine[r] + ypar[r]) * inv);
      int row = wt * 16 + lr;
      int colb = h * 64 + sh * 32 + lg * 8;
      *reinterpret_cast<uint2*>(yTile + row * 512 + (colb ^ ((row & 7) << 4))) =
          *reinterpret_cast<const uint2*>(o);
    }
  }

  __syncthreads();  // yTile complete; KV region free

  // W reg-stage helpers (row = tid>>2 in 0..255, two 16B chunks)
  const int wrow = tid >> 2;
  const int wcb = (tid & 3) * 2;
  float4 wreg[2][4];
  auto WLOAD = [&](int kt, float4* r4) {
    const float* s = Wp + (size_t)wrow * CEMB + kt * 64 + wcb * 8;
    r4[0] = reinterpret_cast<const float4*>(s)[0];
    r4[1] = reinterpret_cast<const float4*>(s)[1];
    r4[2] = reinterpret_cast<const float4*>(s)[2];
    r4[3] = reinterpret_cast<const float4*>(s)[3];
  };
  auto WWRITE = [&](const float4* r4, int bn) {
#pragma unroll
    for (int jj = 0; jj < 2; ++jj) {
      int byte = bn * 32768 + wrow * 128 + (((wcb + jj) * 16) ^ ((wrow & 7) << 4));
      *reinterpret_cast<uint4*>(reinterpret_cast<char*>(ldsKV) + byte) =
          cvt8(r4[jj * 2], r4[jj * 2 + 1]);
    }
  };

  WLOAD(0, wreg[0]);  // latency covered by mean epilogue below

  // ---- head-mean epilogue (wave-private staging in KV region) ----
  {
    float* smem = reinterpret_cast<float*>(ldsKV);
    float* smw = smem + w * (16 * 65) + lr * 65;
    const int trow = l >> 2;
    const int cql = (l & 3) * 4;
    const float* srcp = smem + w * (16 * 65) + trow * 65 + cql;
    float* gdst = mean_out + (size_t)(b * TSEG + tbase + trow) * TSEG + sh * 128 + cql;
    for (int c = 0; c < 2; ++c) {
#pragma unroll
      for (int j = 0; j < 4; ++j) {
        int st = 4 * c + j;
        int sl = 32 * ((st >> 1) & 1) + 4 * (st & 1) + 8 * lg;
#pragma unroll
        for (int r = 0; r < 4; ++r) smw[sl + r] = macc[st][r] * 0.125f;
      }
#pragma unroll
      for (int j = 0; j < 4; ++j)
        *reinterpret_cast<f32x4*>(gdst + c * 64 + j * 16) =
            *reinterpret_cast<const f32x4*>(srcp + j * 16);
    }
  }
  __syncthreads();  // mean staging done; KV region free for W dbuf

  // ---- fused output projection: out = y * Wp^T + bp ----
  {
    const int wrP = w >> 2, wcP = w & 3;

    WWRITE(wreg[0], 0);
    WLOAD(1, wreg[1]);
    __syncthreads();

    f32x4 acc[2][4];
#pragma unroll
    for (int mf = 0; mf < 2; ++mf)
#pragma unroll
      for (int nf = 0; nf < 4; ++nf) {
        f32x4 z = {0.f, 0.f, 0.f, 0.f};
        acc[mf][nf] = z;
      }

#pragma unroll
    for (int kt = 0; kt < 4; ++kt) {
      int buf = kt & 1;
      if (kt < 3) WWRITE(wreg[(kt + 1) & 1], buf ^ 1);
      if (kt < 2) WLOAD(kt + 2, wreg[kt & 1]);
      const char* Wb = reinterpret_cast<const char*>(ldsKV) + buf * 32768;
      bf16x8 av[2][2], bw[4][2];
#pragma unroll
      for (int mf = 0; mf < 2; ++mf)
#pragma unroll
        for (int kk = 0; kk < 2; ++kk) {
          int row = wrP * 32 + mf * 16 + lr;
          int byte = row * 512 + ((kt * 128 + kk * 64 + lg * 16) ^ ((row & 7) << 4));
          av[mf][kk] = *reinterpret_cast<const bf16x8*>(yTile + byte);
        }
#pragma unroll
      for (int nf = 0; nf < 4; ++nf)
#pragma unroll
        for (int kk = 0; kk < 2; ++kk) {
          int row = wcP * 64 + nf * 16 + lr;
          int byte = row * 128 + ((kk * 64 + lg * 16) ^ ((row & 7) << 4));
          bw[nf][kk] = *reinterpret_cast<const bf16x8*>(Wb + byte);
        }
#pragma unroll
      for (int kk = 0; kk < 2; ++kk)
#pragma unroll
        for (int nf = 0; nf < 4; ++nf)
#pragma unroll
          for (int mf = 0; mf < 2; ++mf)
            acc[mf][nf] = __builtin_amdgcn_mfma_f32_16x16x32_bf16(
                av[mf][kk], bw[nf][kk], acc[mf][nf], 0, 0, 0);
      if (kt < 3) __syncthreads();  // last phase: no further LDS access
    }

    float bb[4];
#pragma unroll
    for (int nf = 0; nf < 4; ++nf) bb[nf] = bp[wcP * 64 + nf * 16 + lr];
#pragma unroll
    for (int mf = 0; mf < 2; ++mf)
#pragma unroll
      for (int nf = 0; nf < 4; ++nf)
#pragma unroll
        for (int r = 0; r < 4; ++r) {
          int m = b * TSEG + th * 128 + wrP * 32 + mf * 16 + lg * 4 + r;
          int c = wcP * 64 + nf * 16 + lr;
          out[(size_t)m * CEMB + c] = acc[mf][nf][r] + bb[nf];
        }
  }
}

extern "C" void kernel_launch(void* const* d_in, const int* in_sizes, int n_in,
                              void* d_out, int out_size, void* d_ws, size_t ws_size,
                              hipStream_t stream) {
  (void)in_sizes; (void)n_in; (void)out_size; (void)ws_size;
  const float* x  = (const float*)d_in[0];
  // d_in[1] = batch indices (unused: equal-length segments, B=128, T=256)
  const float* Wq = (const float*)d_in[2];
  const float* bq = (const float*)d_in[3];
  const float* Wk = (const float*)d_in[4];
  const float* bk = (const float*)d_in[5];
  const float* Wv = (const float*)d_in[6];
  const float* bv = (const float*)d_in[7];
  const float* Wp = (const float*)d_in[8];
  const float* bp = (const float*)d_in[9];
  float* out = (float*)d_out;

  char* ws = (char*)d_ws;
  u16* q_ws = (u16*)(ws);                    // 16 MiB, plain [m][256], pre-scaled
  u16* k_ws = (u16*)(ws + 16777216);         // 16 MiB, plain [m][256]
  u16* v_ws = (u16*)(ws + 33554432);         // 16 MiB, transposed [b,h,d,t]
  float* mean_out = out + (size_t)NTOK * CEMB;

  k_qkv<<<256, 1024, 131072, stream>>>(x, Wq, Wk, Wv, bq, bk, bv, q_ws, k_ws, v_ws);
  k_attn<<<256, 1024, 149504, stream>>>(q_ws, k_ws, v_ws, Wp, bp, out, mean_out);
}